// Round 1
// baseline (171.988 us; speedup 1.0000x reference)
//
#include <hip/hip_runtime.h>
#include <stdint.h>

#define B_  8
#define C_  512
#define L_  1024
#define NH_ 8
#define HD_ 64

typedef __attribute__((ext_vector_type(8))) short short8;
typedef __attribute__((ext_vector_type(4))) short short4v;
typedef __attribute__((ext_vector_type(4))) float f32x4;

#define MFMA(a,b,c) __builtin_amdgcn_mfma_f32_16x16x32_bf16((a),(b),(c),0,0,0)
#define GLD16(g,l) __builtin_amdgcn_global_load_lds( \
    (const __attribute__((address_space(1))) void*)(g), \
    (__attribute__((address_space(3))) void*)(l), 16, 0, 0)

__device__ __forceinline__ unsigned short f2bf(float f) {
  union { float f; unsigned u; } x; x.f = f;
  unsigned r = x.u + 0x7FFFu + ((x.u >> 16) & 1u);
  return (unsigned short)(r >> 16);
}

// ---------------- transpose: [B,C,L] f32 -> [B,L,C] bf16 ----------------
__global__ __launch_bounds__(256) void k_transpose(
    const float* __restrict__ q, const float* __restrict__ k,
    unsigned short* __restrict__ qf, unsigned short* __restrict__ kf) {
  __shared__ float t[32][33];
  const int z = blockIdx.z;
  const int b = z >> 1;
  const float* src = (z & 1) ? k : q;
  unsigned short* dst = (z & 1) ? kf : qf;
  const int tx = threadIdx.x & 31;
  const int ty = threadIdx.x >> 5;           // 0..7
  const int l0 = blockIdx.x * 32;
  const int c0 = blockIdx.y * 32;
#pragma unroll
  for (int i = 0; i < 4; ++i)
    t[ty + 8*i][tx] = src[((size_t)b * C_ + c0 + ty + 8*i) * L_ + l0 + tx];
  __syncthreads();
#pragma unroll
  for (int i = 0; i < 4; ++i)
    dst[((size_t)b * L_ + l0 + ty + 8*i) * C_ + c0 + tx] = f2bf(t[tx][ty + 8*i]);
}

// ---------------- weight convert f32 -> bf16 ----------------
__global__ __launch_bounds__(256) void k_convw(
    const float* __restrict__ w0, const float* __restrict__ w1,
    const float* __restrict__ w2, const float* __restrict__ w3,
    unsigned short* __restrict__ dst) {
  const int z = blockIdx.y;
  const float* s = (z == 0) ? w0 : (z == 1) ? w1 : (z == 2) ? w2 : w3;
  unsigned short* d = dst + (size_t)z * (C_ * C_);
  const int i = (blockIdx.x * 256 + threadIdx.x) * 4;
  float4 v = *(const float4*)&s[i];
  short4v p;
  p[0] = (short)f2bf(v.x); p[1] = (short)f2bf(v.y);
  p[2] = (short)f2bf(v.z); p[3] = (short)f2bf(v.w);
  *(short4v*)&d[i] = p;
}

// ---------------- GEMM core: C[m,n] = sum_k A[m,k]*W[n,k]  (128x128 tile, BK=64) ----
// mode 0: Q -> [B,NH,L,64] bf16, (acc+bias)*scale
// mode 1: K -> [B,NH,L,64] bf16, acc+bias
// mode 2: V -> [B,NH,64,L] bf16 (transposed), acc+bias
// mode 3: out-proj -> [B,C,L] f32, acc+bias+resQ+resK
__device__ __forceinline__ void gemm_core(
    const unsigned short* __restrict__ A, const unsigned short* __restrict__ W,
    const float* __restrict__ bias, void* __restrict__ outp,
    const float* __restrict__ resQ, const float* __restrict__ resK,
    int mode, float scale, unsigned short* lA, unsigned short* lB) {
  const int lane = threadIdx.x & 63;
  const int wid  = threadIdx.x >> 6;
  const int wm = wid >> 1, wn = wid & 1;
  const int tm = blockIdx.x * 128;
  const int tn = blockIdx.y * 128;
  const int r16 = lane & 15;
  const int g4  = lane >> 4;

  f32x4 acc[4][4];
#pragma unroll
  for (int i = 0; i < 4; ++i)
#pragma unroll
    for (int j = 0; j < 4; ++j) acc[i][j] = (f32x4){0.f, 0.f, 0.f, 0.f};

  for (int kt = 0; kt < C_; kt += 64) {
#pragma unroll
    for (int i = 0; i < 4; ++i) {
      int chunk = wid * 4 + i;
      int row = chunk * 8 + (lane >> 3);
      int col = (lane & 7) * 8;
      GLD16(A + (size_t)(tm + row) * C_ + kt + col, &lA[chunk * 512]);
    }
#pragma unroll
    for (int i = 0; i < 4; ++i) {
      int chunk = wid * 4 + i;
      int row = chunk * 8 + (lane >> 3);
      int col = (lane & 7) * 8;
      GLD16(W + (size_t)(tn + row) * C_ + kt + col, &lB[chunk * 512]);
    }
    __syncthreads();
#pragma unroll
    for (int ks = 0; ks < 2; ++ks) {
      const int co = ks * 32 + g4 * 8;
      short8 af[4], bw[4];
#pragma unroll
      for (int i = 0; i < 4; ++i) af[i] = *(const short8*)&lA[(wm*64 + i*16 + r16) * 64 + co];
#pragma unroll
      for (int j = 0; j < 4; ++j) bw[j] = *(const short8*)&lB[(wn*64 + j*16 + r16) * 64 + co];
#pragma unroll
      for (int i = 0; i < 4; ++i)
#pragma unroll
        for (int j = 0; j < 4; ++j) acc[i][j] = MFMA(af[i], bw[j], acc[i][j]);
    }
    __syncthreads();
  }

  if (mode <= 1) {
    unsigned short* out = (unsigned short*)outp;
#pragma unroll
    for (int i = 0; i < 4; ++i)
#pragma unroll
      for (int j = 0; j < 4; ++j) {
        int c = tn + wn*64 + j*16 + r16;
        float bia = bias[c];
        int h = c >> 6, d = c & 63;
#pragma unroll
        for (int r = 0; r < 4; ++r) {
          int gm = tm + wm*64 + i*16 + g4*4 + r;
          int b = gm >> 10, l = gm & 1023;
          out[(((size_t)b * NH_ + h) * L_ + l) * HD_ + d] = f2bf((acc[i][j][r] + bia) * scale);
        }
      }
  } else if (mode == 2) {
    unsigned short* out = (unsigned short*)outp;
#pragma unroll
    for (int i = 0; i < 4; ++i)
#pragma unroll
      for (int j = 0; j < 4; ++j) {
        int c = tn + wn*64 + j*16 + r16;
        float bia = bias[c];
        int h = c >> 6, d = c & 63;
        int gm0 = tm + wm*64 + i*16 + g4*4;
        int b = gm0 >> 10, l0 = gm0 & 1023;
        short4v pk;
#pragma unroll
        for (int r = 0; r < 4; ++r) pk[r] = (short)f2bf(acc[i][j][r] + bia);
        *(short4v*)&out[(((size_t)b * NH_ + h) * HD_ + d) * L_ + l0] = pk;
      }
  } else {
    float* out = (float*)outp;
#pragma unroll
    for (int i = 0; i < 4; ++i)
#pragma unroll
      for (int j = 0; j < 4; ++j) {
        int c = tn + wn*64 + j*16 + r16;
        float bia = bias[c];
        int gm0 = tm + wm*64 + i*16 + g4*4;
        int b = gm0 >> 10, l0 = gm0 & 1023;
        size_t idx = ((size_t)b * C_ + c) * L_ + l0;
        float4 q4 = *(const float4*)&resQ[idx];
        float4 k4 = *(const float4*)&resK[idx];
        float4 o4;
        o4.x = acc[i][j][0] + bia + q4.x + k4.x;
        o4.y = acc[i][j][1] + bia + q4.y + k4.y;
        o4.z = acc[i][j][2] + bia + q4.z + k4.z;
        o4.w = acc[i][j][3] + bia + q4.w + k4.w;
        *(float4*)&out[idx] = o4;
      }
  }
}

__global__ __launch_bounds__(256) void k_proj(
    const unsigned short* __restrict__ qf, const unsigned short* __restrict__ kf,
    const unsigned short* __restrict__ Wqb, const unsigned short* __restrict__ Wkb,
    const unsigned short* __restrict__ Wvb,
    const float* __restrict__ bq, const float* __restrict__ bk, const float* __restrict__ bv,
    unsigned short* __restrict__ Qw, unsigned short* __restrict__ Kw,
    unsigned short* __restrict__ VTw) {
  __shared__ unsigned short lA[128 * 64];
  __shared__ unsigned short lB[128 * 64];
  const int z = blockIdx.z;
  const unsigned short* A = (z == 0) ? qf : kf;
  const unsigned short* W = (z == 0) ? Wqb : (z == 1) ? Wkb : Wvb;
  const float* bias = (z == 0) ? bq : (z == 1) ? bk : bv;
  void* out = (z == 0) ? (void*)Qw : (z == 1) ? (void*)Kw : (void*)VTw;
  float scale = (z == 0) ? 0.125f : 1.0f;
  gemm_core(A, W, bias, out, nullptr, nullptr, z, scale, lA, lB);
}

__global__ __launch_bounds__(256) void k_outproj(
    const unsigned short* __restrict__ O, const unsigned short* __restrict__ Wob,
    const float* __restrict__ bo, float* __restrict__ out,
    const float* __restrict__ query, const float* __restrict__ key) {
  __shared__ unsigned short lA[128 * 64];
  __shared__ unsigned short lB[128 * 64];
  gemm_core(O, Wob, bo, out, query, key, 3, 1.0f, lA, lB);
}

// ---------------- flash attention ----------------
// Q,K: [B,NH,L,64] bf16 (Q pre-scaled), VT: [B,NH,64,L] bf16, O: [B,L,C] bf16
__global__ __launch_bounds__(256) void k_attn(
    const unsigned short* __restrict__ Q, const unsigned short* __restrict__ K,
    const unsigned short* __restrict__ VT, unsigned short* __restrict__ O) {
  __shared__ unsigned short Pl[4][32 * 136];   // per-wave P tile, 272B row stride
  const int lane = threadIdx.x & 63;
  const int wid  = threadIdx.x >> 6;
  const int bh = blockIdx.y;
  const int qrow0 = blockIdx.x * 128 + wid * 32;
  const int r16 = lane & 15;
  const int g4  = lane >> 4;
  const size_t base = (size_t)bh * L_ * HD_;

  short8 qv[2][2];
#pragma unroll
  for (int i = 0; i < 2; ++i)
#pragma unroll
    for (int ks = 0; ks < 2; ++ks)
      qv[i][ks] = *(const short8*)(Q + base + (size_t)(qrow0 + i*16 + r16) * HD_ + ks*32 + g4*8);

  float m_run[2][4], l_run[2][4];
  f32x4 oacc[2][4];
#pragma unroll
  for (int i = 0; i < 2; ++i)
#pragma unroll
    for (int r = 0; r < 4; ++r) { m_run[i][r] = -1e30f; l_run[i][r] = 0.f; }
#pragma unroll
  for (int i = 0; i < 2; ++i)
#pragma unroll
    for (int j = 0; j < 4; ++j) oacc[i][j] = (f32x4){0.f, 0.f, 0.f, 0.f};

  unsigned short* myP = &Pl[wid][0];

  for (int kt = 0; kt < L_; kt += 128) {
    f32x4 s[2][8];
#pragma unroll
    for (int i = 0; i < 2; ++i)
#pragma unroll
      for (int cf = 0; cf < 8; ++cf) s[i][cf] = (f32x4){0.f, 0.f, 0.f, 0.f};

#pragma unroll
    for (int cf = 0; cf < 8; ++cf) {
      const unsigned short* kp = K + base + (size_t)(kt + cf*16 + r16) * HD_ + g4*8;
      short8 kb0 = *(const short8*)(kp);
      short8 kb1 = *(const short8*)(kp + 32);
#pragma unroll
      for (int i = 0; i < 2; ++i) {
        s[i][cf] = MFMA(qv[i][0], kb0, s[i][cf]);
        s[i][cf] = MFMA(qv[i][1], kb1, s[i][cf]);
      }
    }
    // online softmax
#pragma unroll
    for (int i = 0; i < 2; ++i)
#pragma unroll
      for (int r = 0; r < 4; ++r) {
        float mx = s[i][0][r];
#pragma unroll
        for (int cf = 1; cf < 8; ++cf) mx = fmaxf(mx, s[i][cf][r]);
#pragma unroll
        for (int off = 8; off; off >>= 1) mx = fmaxf(mx, __shfl_xor(mx, off, 16));
        float mn = fmaxf(m_run[i][r], mx);
        float fsc = __expf(m_run[i][r] - mn);
        m_run[i][r] = mn;
        float sum = 0.f;
#pragma unroll
        for (int cf = 0; cf < 8; ++cf) {
          float p = __expf(s[i][cf][r] - mn);
          s[i][cf][r] = p;
          sum += p;
        }
#pragma unroll
        for (int off = 8; off; off >>= 1) sum += __shfl_xor(sum, off, 16);
        l_run[i][r] = l_run[i][r] * fsc + sum;
#pragma unroll
        for (int j = 0; j < 4; ++j) oacc[i][j][r] *= fsc;
      }
    // P -> LDS (bf16)
#pragma unroll
    for (int i = 0; i < 2; ++i)
#pragma unroll
      for (int cf = 0; cf < 8; ++cf)
#pragma unroll
        for (int r = 0; r < 4; ++r)
          myP[(i*16 + g4*4 + r) * 136 + cf*16 + r16] = f2bf(s[i][cf][r]);
    // PV
#pragma unroll
    for (int ksub = 0; ksub < 4; ++ksub) {
      short8 pa0 = *(const short8*)&myP[(r16) * 136 + ksub*32 + g4*8];
      short8 pa1 = *(const short8*)&myP[(16 + r16) * 136 + ksub*32 + g4*8];
#pragma unroll
      for (int j = 0; j < 4; ++j) {
        short8 vb = *(const short8*)(VT + (size_t)bh * HD_ * L_ +
                                     (size_t)(j*16 + r16) * L_ + kt + ksub*32 + g4*8);
        oacc[0][j] = MFMA(pa0, vb, oacc[0][j]);
        oacc[1][j] = MFMA(pa1, vb, oacc[1][j]);
      }
    }
  }
  const int b = bh >> 3, h = bh & 7;
#pragma unroll
  for (int i = 0; i < 2; ++i)
#pragma unroll
    for (int j = 0; j < 4; ++j)
#pragma unroll
      for (int r = 0; r < 4; ++r) {
        int row = qrow0 + i*16 + g4*4 + r;
        int col = h*64 + j*16 + r16;
        O[((size_t)b * L_ + row) * C_ + col] = f2bf(oacc[i][j][r] / l_run[i][r]);
      }
}

extern "C" void kernel_launch(void* const* d_in, const int* in_sizes, int n_in,
                              void* d_out, int out_size, void* d_ws, size_t ws_size,
                              hipStream_t stream) {
  (void)in_sizes; (void)n_in; (void)out_size; (void)ws_size;
  const float* query = (const float*)d_in[0];
  const float* key   = (const float*)d_in[1];
  const float* Wq = (const float*)d_in[2];
  const float* bq = (const float*)d_in[3];
  const float* Wk = (const float*)d_in[4];
  const float* bk = (const float*)d_in[5];
  const float* Wv = (const float*)d_in[6];
  const float* bv = (const float*)d_in[7];
  const float* Wo = (const float*)d_in[8];
  const float* bo = (const float*)d_in[9];

  char* ws = (char*)d_ws;
  unsigned short* qf  = (unsigned short*)(ws);                  // 8 MB
  unsigned short* kf  = (unsigned short*)(ws + 8388608);        // 8 MB
  unsigned short* Wqb = (unsigned short*)(ws + 16777216);       // 4x 512KB
  unsigned short* Wkb = Wqb + 262144;
  unsigned short* Wvb = Wkb + 262144;
  unsigned short* Wob = Wvb + 262144;
  unsigned short* Qw  = (unsigned short*)(ws + 18874368);       // 8 MB
  unsigned short* Kw  = (unsigned short*)(ws + 27262976);       // 8 MB
  unsigned short* VTw = (unsigned short*)(ws + 35651584);       // 8 MB
  unsigned short* Ow  = (unsigned short*)(ws + 44040192);       // 8 MB

  k_transpose<<<dim3(32, 16, 16), 256, 0, stream>>>(query, key, qf, kf);
  k_convw<<<dim3(256, 4), 256, 0, stream>>>(Wq, Wk, Wv, Wo, Wqb);
  k_proj<<<dim3(64, 4, 3), 256, 0, stream>>>(qf, kf, Wqb, Wkb, Wvb, bq, bk, bv, Qw, Kw, VTw);
  k_attn<<<dim3(8, 64), 256, 0, stream>>>(Qw, Kw, VTw, Ow);
  k_outproj<<<dim3(64, 4), 256, 0, stream>>>(Ow, Wob, bo, (float*)d_out, query, key);
}